// Round 13
// baseline (462.684 us; speedup 1.0000x reference)
//
#include <hip/hip_runtime.h>

#define B_SZ 1024
#define T_SZ 128
#define HID 512
#define LAB 100

// ---- d_ws layout (byte offsets) ----
#define OFF_XC    0u          // uchar2 t-major [128][1024][2] = 256 KB
#define OFF_WEFFT 262144u     // float[128][512] Weff^T        = 256 KB
#define OFF_BEFF  524288u     // float[512]
#define OFF_ELEN  526336u     // ushort[256][512] bf16 (n-permuted) = 256 KB
#define OFF_EIPD  788480u     // ushort[256][512] bf16 (n-permuted) = 256 KB
#define OFF_FLAGS 1050624u    // uint[3]: flagW, flagX, flagT
#define WS_NEED   1050640u

typedef __attribute__((ext_vector_type(8))) short short8;
typedef __attribute__((ext_vector_type(8))) unsigned short us8;
typedef __attribute__((ext_vector_type(4))) float float4v;
typedef __attribute__((ext_vector_type(4))) unsigned short us4;
typedef __attribute__((ext_vector_type(8))) __bf16 bf8_t;
typedef unsigned long long ull;

__device__ __attribute__((aligned(16))) unsigned char g_blob[WS_NEED]; // fallback only

__device__ __forceinline__ float bf2f(unsigned short u) {
    union { unsigned int i; float f; } z; z.i = ((unsigned int)u) << 16; return z.f;
}
__device__ __forceinline__ unsigned short f2bf(float f) {
    union { float f; unsigned int i; } z; z.f = f;
    unsigned int r = z.i + 0x7FFFu + ((z.i >> 16) & 1u);
    return (unsigned short)(r >> 16);
}
__device__ __forceinline__ float4v mfma16(short8 a, short8 b, float4v c) {
    return __builtin_amdgcn_mfma_f32_16x16x32_bf16(
        __builtin_bit_cast(bf8_t, a), __builtin_bit_cast(bf8_t, b), c, 0, 0, 0);
}

__global__ void zero_kernel(unsigned int* __restrict__ flags) {
    if (threadIdx.x < 3) flags[threadIdx.x] = 0u;
}

// ---------------------------------------------------------------------------
// FUSED everything-kernel: 192 blocks x 512 threads, 160 KB dyn LDS
// (1 block/CU -> all 192 co-resident on 256 CUs -> flag-spin deadlock-free).
// r12 CRASH FIX: the XC role's `__shared__ int is64` added static LDS on top
// of the 163840-byte dynamic allocation -> >160 KB/CU -> launch abort. NO
// static __shared__ allowed anywhere in this kernel; is64 is now computed
// per-thread from uniform scalar loads (L1-broadcast, no barrier).
// Roles (ascending blockIdx = dependency order):
//  [0,32)    WEFF:  Weff^T[k][n] = sum_j x2h[n][j]*fc1[j][k]  -> flagW +=1
//  [32]      BEFF:  beff[n] (f32 exact)                       -> flagW +=1
//  [33,64)   XC:    x -> uchar2 t-major                       -> flagX +=1
//  [64,128)  TABLE: spin flagW==33; bf16 tables, N-PERMUTED:
//                   n = w*64+nt*16+qq*4+r -> p = w*64+(nt>>1)*32+qq*8+(nt&1)*4+r
//                   -> flagT +=1
//  [128,192) RNN:   v7 structure; Wh/fc2 converted INLINE from f32 (value-
//                   identical f2bf) so the long prologue has no prep deps;
//                   spins flagX==31 && flagT==64 only before the gather
//                   prologue. Gather = 4 x us8 loads/thread/step (was 8 x us4)
//                   -> 64 L1 line-transactions/wave/step (r11 lesson: gather
//                   cost is line count, not bytes).
// Sync protocol = r6-proven: producer __syncthreads -> tid0 threadfence +
// system-scope release add; consumer tid0 relaxed spin + acquire threadfence
// -> __syncthreads.
// ---------------------------------------------------------------------------
__launch_bounds__(512, 2)
__global__ void fused_kernel(const int* __restrict__ xi,
                             const float* __restrict__ len_f, const float* __restrict__ ipd_f,
                             const float* __restrict__ fc1_f, const float* __restrict__ fc1b_f,
                             const float* __restrict__ x2h_f, const float* __restrict__ x2hb_f,
                             const float* __restrict__ h2h_f, const float* __restrict__ h2hb_f,
                             const float* __restrict__ fc2_f, const float* __restrict__ fc2b_f,
                             unsigned char* __restrict__ xc,
                             float* __restrict__ wefft, float* __restrict__ beff,
                             unsigned short* __restrict__ elen, unsigned short* __restrict__ eipd,
                             unsigned int* __restrict__ flags,
                             float* __restrict__ out) {
    extern __shared__ unsigned short sm2[];
    const int tid = threadIdx.x;
    const int b   = blockIdx.x;

    if (b < 32) {
        // ---------------- WEFF producer ----------------
        int gid = b * 512 + tid;              // 0..16383
        int n  = gid >> 5;                    // 0..511 (32 threads per n)
        int k0 = (gid & 31) * 4;
        const float* xr = x2h_f + n * 128;
        float a0 = 0.f, a1 = 0.f, a2 = 0.f, a3 = 0.f;
#pragma unroll 4
        for (int j = 0; j < 128; j++) {
            float xv = xr[j];                                      // broadcast
            float4v fv = *(const float4v*)(fc1_f + j * 128 + k0);  // coalesced
            a0 += xv * fv[0]; a1 += xv * fv[1];
            a2 += xv * fv[2]; a3 += xv * fv[3];
        }
        wefft[(k0 + 0) * 512 + n] = a0;
        wefft[(k0 + 1) * 512 + n] = a1;
        wefft[(k0 + 2) * 512 + n] = a2;
        wefft[(k0 + 3) * 512 + n] = a3;
        __syncthreads();
        if (tid == 0) {
            __threadfence();
            __hip_atomic_fetch_add(&flags[0], 1u, __ATOMIC_RELEASE, __HIP_MEMORY_SCOPE_SYSTEM);
        }
        return;
    }
    if (b == 32) {
        // ---------------- BEFF producer ----------------
        float s = x2hb_f[tid] + h2hb_f[tid];
        const float4v* xr = (const float4v*)(x2h_f + tid * 128);
        const float4v* bb = (const float4v*)fc1b_f;
        for (int j = 0; j < 32; j++) {
            float4v a = xr[j], c = bb[j];
            s += a[0] * c[0] + a[1] * c[1] + a[2] * c[2] + a[3] * c[3];
        }
        beff[tid] = s;
        __syncthreads();
        if (tid == 0) {
            __threadfence();
            __hip_atomic_fetch_add(&flags[0], 1u, __ATOMIC_RELEASE, __HIP_MEMORY_SCOPE_SYSTEM);
        }
        return;
    }
    if (b < 64) {
        // ---------------- XC producer (31 blocks) ----------------
        // is64 check per-thread: uniform scalar loads, no shared memory
        // (r12 lesson: NO static __shared__ in a 160KB-dyn-LDS kernel).
        int nz = 0;
        for (int j = 1; j < 64; j += 2) nz |= xi[j];
        const int i64 = (nz == 0) ? 1 : 0;
        const int n = B_SZ * T_SZ * 2;
        for (int i = (b - 33) * 512 + tid; i < n; i += 31 * 512) {
            int v = i64 ? xi[2 * i] : xi[i];
            v = v < 0 ? 0 : (v > 255 ? 255 : v);
            int bb2 = i >> 8, r = i & 255, t = r >> 1, c = r & 1;
            xc[t * 2048 + bb2 * 2 + c] = (unsigned char)v;
        }
        __syncthreads();
        if (tid == 0) {
            __threadfence();
            __hip_atomic_fetch_add(&flags[1], 1u, __ATOMIC_RELEASE, __HIP_MEMORY_SCOPE_SYSTEM);
        }
        return;
    }
    if (b < 128) {
        // ---------------- TABLE builder (64 blocks, 2 outputs/thread) -------
        if (tid == 0) {
            while (__hip_atomic_load(&flags[0], __ATOMIC_RELAXED, __HIP_MEMORY_SCOPE_SYSTEM) < 33u)
                __builtin_amdgcn_s_sleep(8);
            __threadfence();   // acquire: wefft/beff reads below
        }
        __syncthreads();
        int gid = (b - 64) * 512 + tid;        // 0..32767
#pragma unroll
        for (int ii = 0; ii < 2; ii++) {
            int grp = gid + ii * 32768;        // 0..65535
            int tab = grp >> 15;               // 0: len, 1: ipd
            int g2  = grp & 32767;
            int v   = g2 >> 7;
            int nq  = (g2 & 127) * 4;          // logical n base (4 consecutive)
            const float* emb = (tab ? ipd_f : len_f) + v * 64;
            const float* wt  = wefft + tab * 64 * 512 + nq;
            float a0 = 0.f, a1 = 0.f, a2 = 0.f, a3 = 0.f;
#pragma unroll 8
            for (int k = 0; k < 64; k++) {
                float e = emb[k];
                float4v w = *(const float4v*)(wt + k * 512);
                a0 += e * w[0]; a1 += e * w[1]; a2 += e * w[2]; a3 += e * w[3];
            }
            if (tab) {
                float4v b4 = *(const float4v*)&beff[nq];
                a0 += b4[0]; a1 += b4[1]; a2 += b4[2]; a3 += b4[3];
            }
            // permuted store: n = w*64 + nt*16 + qq*4 + r ->
            //                 p = w*64 + (nt>>1)*32 + qq*8 + (nt&1)*4 + r
            int nt = (nq >> 4) & 3, qq = (nq >> 2) & 3;
            int p0 = (nq & ~63) + ((nt >> 1) << 5) + qq * 8 + ((nt & 1) << 2);
            us4 o = { f2bf(a0), f2bf(a1), f2bf(a2), f2bf(a3) };
            unsigned short* dst = tab ? eipd : elen;
            *(us4*)&dst[v * 512 + p0] = o;
        }
        __syncthreads();
        if (tid == 0) {
            __threadfence();
            __hip_atomic_fetch_add(&flags[2], 1u, __ATOMIC_RELEASE, __HIP_MEMORY_SCOPE_SYSTEM);
        }
        return;
    }

    // ==================== RNN role (blocks 128..191) ========================
    unsigned short* sA = sm2;            // Wh k 384..511 bf16 swizzled (128 KB)
    unsigned short* sH = sm2 + 65536;    // h dbuf: 2 x 8192 ushorts (32 KB)

    const int wv   = tid >> 6;           // 0..7
    const int ln   = tid & 63;
    const int mcol = ln & 15;            // batch col within block
    const int q    = ln >> 4;
    const int g    = b - 128;
    const int b0   = g * 16;
    const int n0   = wv * 64;            // wave owns hidden rows n0..n0+63

    // ---- stage Wh kt 12..15 into LDS, INLINE f32->bf16 (swizzled) ----
    for (int it = 0; it < 16; it++) {
        int chunk = it * 512 + tid;          // 0..8191
        int r = chunk >> 4, c = chunk & 15;
        const float* s = h2h_f + r * 512 + 384 + c * 8;
        float4v a = *(const float4v*)s;
        float4v d = *(const float4v*)(s + 4);
        us4 lo = { f2bf(a[0]), f2bf(a[1]), f2bf(a[2]), f2bf(a[3]) };
        us4 hi = { f2bf(d[0]), f2bf(d[1]), f2bf(d[2]), f2bf(d[3]) };
        unsigned short* dst = &sA[r * 128 + ((c ^ (r & 15)) & 15) * 8];
        *(us4*)dst = lo;
        *(us4*)(dst + 4) = hi;
    }
    // ---- zero h buffer 0 ----
    {
        uint4 z = {0, 0, 0, 0};
        *(uint4*)&sH[tid * 8] = z;
        *(uint4*)&sH[(512 + tid) * 8] = z;
    }
    // ---- Wh kt 0..11 into registers (192 AGPR), INLINE f32->bf16 ----
    short8 whr[4][12];
#pragma unroll
    for (int nt = 0; nt < 4; nt++)
#pragma unroll
        for (int kt = 0; kt < 12; kt++) {
            const float* s = h2h_f + (n0 + nt * 16 + mcol) * 512 + kt * 32 + q * 8;
            float4v a = *(const float4v*)s;
            float4v d = *(const float4v*)(s + 4);
            short8 w8 = { (short)f2bf(a[0]), (short)f2bf(a[1]), (short)f2bf(a[2]), (short)f2bf(a[3]),
                          (short)f2bf(d[0]), (short)f2bf(d[1]), (short)f2bf(d[2]), (short)f2bf(d[3]) };
            whr[nt][kt] = w8;
        }

    // ---- strength-reduced swizzle offsets (ushort units) ----
    const int qlo = (q ^ (mcol & 3)) * 8;
    int ej[4];
#pragma unroll
    for (int j = 0; j < 4; j++)
        ej[j] = ((j * 4) ^ (mcol & 12)) * 8;
    const int base_b = mcol * 512 + qlo;          // h-read base
    const int fbase  = (n0 + mcol) * 128 + qlo;   // sA-read base
    int hw_off[4];
#pragma unroll
    for (int nt = 0; nt < 4; nt++) {
        int n = n0 + nt * 16 + q * 4;
        hw_off[nt] = mcol * 512 + (((n >> 3) ^ mcol) & 63) * 8 + (n & 7);
    }

    // ---- wait for xc + tables (producers finished under our staging) ----
    if (tid == 0) {
        while (__hip_atomic_load(&flags[1], __ATOMIC_RELAXED, __HIP_MEMORY_SCOPE_SYSTEM) < 31u ||
               __hip_atomic_load(&flags[2], __ATOMIC_RELAXED, __HIP_MEMORY_SCOPE_SYSTEM) < 64u)
            __builtin_amdgcn_s_sleep(8);
        __threadfence();   // acquire for xc/table reads
    }
    __syncthreads();        // also covers sA/sH staging visibility

    // ---- gather pipeline prologue (permuted bf16 tables, uchar2 idx) ----
    const int xb2  = (b0 + mcol) * 2;     // byte offset within a t-slice
    const int ecol = n0 + q * 8;          // permuted window offset
    us8 tL0, tL1, tI0, tI1;
    {
        unsigned int i0 = *(const unsigned short*)&xc[xb2];            // x[t=0]
        const unsigned short* eL = elen + (i0 & 255u) * 512 + ecol;
        const unsigned short* eI = eipd + (i0 >> 8) * 512 + ecol;
        tL0 = *(const us8*)eL;  tL1 = *(const us8*)(eL + 32);
        tI0 = *(const us8*)eI;  tI1 = *(const us8*)(eI + 32);
    }
    unsigned int idxP = *(const unsigned short*)&xc[2048 + xb2];       // x[t=1]

    for (int t = 0; t < T_SZ; t++) {
        const unsigned short* hRd = sH + ((t & 1) << 13);
        unsigned short* hWr = sH + (((t + 1) & 1) << 13);

        // ---- acc init: unpack permuted us8 pairs (loads from t-1, landed) --
        float4v acc[4];
#pragma unroll
        for (int r = 0; r < 4; r++) {
            acc[0][r] = bf2f(tL0[r])     + bf2f(tI0[r]);
            acc[1][r] = bf2f(tL0[4 + r]) + bf2f(tI0[4 + r]);
            acc[2][r] = bf2f(tL1[r])     + bf2f(tI1[r]);
            acc[3][r] = bf2f(tL1[4 + r]) + bf2f(tI1[4 + r]);
        }
        // ---- issue next-step table loads (idxP resident -> no chain) ----
        if (t + 1 < T_SZ) {
            const unsigned short* eL = elen + (idxP & 255u) * 512 + ecol;
            const unsigned short* eI = eipd + (idxP >> 8) * 512 + ecol;
            tL0 = *(const us8*)eL;  tL1 = *(const us8*)(eL + 32);
            tI0 = *(const us8*)eI;  tI1 = *(const us8*)(eI + 32);
            if (t + 2 < T_SZ)
                idxP = *(const unsigned short*)&xc[(t + 2) * 2048 + xb2];
        }

        // ---- Wh MFMAs: kt 0..11 from regs ----
#pragma unroll
        for (int kt = 0; kt < 12; kt++) {
            short8 bh = *(const short8*)&hRd[base_b + ej[kt & 3] + (kt >> 2) * 128];
#pragma unroll
            for (int nt = 0; nt < 4; nt++)
                acc[nt] = mfma16(whr[nt][kt], bh, acc[nt]);
        }
        // ---- kt 12..15 from LDS ----
#pragma unroll
        for (int j = 0; j < 4; j++) {
            short8 bh = *(const short8*)&hRd[base_b + ej[j] + 384];
#pragma unroll
            for (int nt = 0; nt < 4; nt++) {
                short8 fa = *(const short8*)&sA[fbase + nt * 2048 + ej[j]];
                acc[nt] = mfma16(fa, bh, acc[nt]);
            }
        }

        // ---- fast tanh -> bf16, write h(t+1) into other buffer ----
#pragma unroll
        for (int nt = 0; nt < 4; nt++) {
            unsigned short o[4];
#pragma unroll
            for (int r = 0; r < 4; r++) {
                float e  = __expf(2.0f * acc[nt][r]);
                float th = 1.0f - 2.0f * __builtin_amdgcn_rcpf(e + 1.0f);
                o[r] = f2bf(th);
            }
            us4 v4 = { o[0], o[1], o[2], o[3] };
            *(us4*)&hWr[hw_off[nt]] = v4;
        }
        __syncthreads();   // h(t+1) visible to all waves before next step
    }

    // final h is in buffer 0 (T_SZ even)
    unsigned short* hF = sH;

    // ---- fc2 epilogue: INLINE f32->bf16 fc2; waves 0..6 cover 100 labels ---
    if (wv < 7) {
        int lA = wv * 16 + mcol; if (lA > 99) lA = 99;
        float4v a2 = {0.f, 0.f, 0.f, 0.f};
#pragma unroll
        for (int kt = 0; kt < 16; kt++) {
            const float* s = fc2_f + lA * 512 + kt * 32 + q * 8;
            float4v fa0 = *(const float4v*)s;
            float4v fa1 = *(const float4v*)(s + 4);
            short8 fa = { (short)f2bf(fa0[0]), (short)f2bf(fa0[1]), (short)f2bf(fa0[2]), (short)f2bf(fa0[3]),
                          (short)f2bf(fa1[0]), (short)f2bf(fa1[1]), (short)f2bf(fa1[2]), (short)f2bf(fa1[3]) };
            short8 bh = *(const short8*)&hF[base_b + ej[kt & 3] + (kt >> 2) * 128];
            a2 = mfma16(fa, bh, a2);
        }
#pragma unroll
        for (int r = 0; r < 4; r++) {
            int l = wv * 16 + q * 4 + r;
            if (l < 100) out[(b0 + mcol) * 100 + l] = a2[r] + fc2b_f[l];
        }
    }
}

extern "C" void kernel_launch(void* const* d_in, const int* in_sizes, int n_in,
                              void* d_out, int out_size, void* d_ws, size_t ws_size,
                              hipStream_t stream) {
    unsigned char* base = (unsigned char*)d_ws;
    if (ws_size < (size_t)WS_NEED) {
        void* p = nullptr;
        hipGetSymbolAddress(&p, HIP_SYMBOL(g_blob));
        base = (unsigned char*)p;
    }
    unsigned char*  w_xc    = base + OFF_XC;
    float*          w_wefft = (float*)(base + OFF_WEFFT);
    float*          w_beff  = (float*)(base + OFF_BEFF);
    unsigned short* w_elen  = (unsigned short*)(base + OFF_ELEN);
    unsigned short* w_eipd  = (unsigned short*)(base + OFF_EIPD);
    unsigned int*   w_flags = (unsigned int*)(base + OFF_FLAGS);

    static bool attr_set = false;
    if (!attr_set) {
        hipFuncSetAttribute((const void*)fused_kernel,
                            hipFuncAttributeMaxDynamicSharedMemorySize, 163840);
        attr_set = true;
    }

    zero_kernel<<<1, 64, 0, stream>>>(w_flags);
    fused_kernel<<<192, 512, 163840, stream>>>(
        (const int*)d_in[0],
        (const float*)d_in[1], (const float*)d_in[2],
        (const float*)d_in[3], (const float*)d_in[4],
        (const float*)d_in[5], (const float*)d_in[6],
        (const float*)d_in[7], (const float*)d_in[8],
        (const float*)d_in[9], (const float*)d_in[10],
        w_xc, w_wefft, w_beff, w_elen, w_eipd, w_flags,
        (float*)d_out);
}

// Round 14
// 354.802 us; speedup vs baseline: 1.3041x; 1.3041x over previous
//
#include <hip/hip_runtime.h>

#define B_SZ 1024
#define T_SZ 128
#define HID 512
#define LAB 100

// ---- d_ws layout (byte offsets) ----
#define OFF_XC    0u          // uchar2 t-major [128][1024][2] = 256 KB
#define OFF_WH    262144u     // ushort[262144] bf16 Wh        = 512 KB
#define OFF_FC2   786432u     // ushort[51200]  bf16 fc2
#define OFF_FC2B  888832u     // float[100] (+pad)
#define OFF_WEFFT 889344u     // float[128][512] Weff^T        = 256 KB
#define OFF_BEFF  1151488u    // float[512]
#define OFF_ELEN  1153536u    // ushort[256][512] bf16 N-PERMUTED = 256 KB
#define OFF_EIPD  1415680u    // ushort[256][512] bf16 N-PERMUTED = 256 KB
#define WS_NEED   1677824u

typedef __attribute__((ext_vector_type(8))) short short8;
typedef __attribute__((ext_vector_type(8))) unsigned short us8;
typedef __attribute__((ext_vector_type(4))) float float4v;
typedef __attribute__((ext_vector_type(4))) unsigned short us4;
typedef __attribute__((ext_vector_type(8))) __bf16 bf8_t;
typedef unsigned long long ull;

__device__ __attribute__((aligned(16))) unsigned char g_blob[WS_NEED]; // fallback only

__device__ __forceinline__ float bf2f(unsigned short u) {
    union { unsigned int i; float f; } z; z.i = ((unsigned int)u) << 16; return z.f;
}
__device__ __forceinline__ unsigned short f2bf(float f) {
    union { float f; unsigned int i; } z; z.f = f;
    unsigned int r = z.i + 0x7FFFu + ((z.i >> 16) & 1u);
    return (unsigned short)(r >> 16);
}
__device__ __forceinline__ float4v mfma16(short8 a, short8 b, float4v c) {
    return __builtin_amdgcn_mfma_f32_16x16x32_bf16(
        __builtin_bit_cast(bf8_t, a), __builtin_bit_cast(bf8_t, b), c, 0, 0, 0);
}

// ---------------------------------------------------------------------------
// K1 (66 blocks x 256): work that must precede the table build (r11-proven).
//  [0,64) : Weff^T[k][n] coalesced mapping (broadcast x2h + float4 fc1 rows)
//  [64,66): beff[n] = x2hb[n]+h2hb[n]+sum_j x2h[n][j]*fc1b[j]  (f32 exact)
// ---------------------------------------------------------------------------
__launch_bounds__(256)
__global__ void k1_kernel(const float* __restrict__ fc1_f, const float* __restrict__ fc1b_f,
                          const float* __restrict__ x2h_f, const float* __restrict__ x2hb_f,
                          const float* __restrict__ h2hb_f,
                          float* __restrict__ wefft, float* __restrict__ beff) {
    const int tid = threadIdx.x;
    if (blockIdx.x < 64) {
        int gid = blockIdx.x * 256 + tid;     // 0..16383
        int n  = gid >> 5;                    // 0..511 (32 threads per n)
        int k0 = (gid & 31) * 4;              // 0,4,...,124
        const float* xr = x2h_f + n * 128;
        float a0 = 0.f, a1 = 0.f, a2 = 0.f, a3 = 0.f;
#pragma unroll 4
        for (int j = 0; j < 128; j++) {
            float xv = xr[j];                             // broadcast in wave
            float4v fv = *(const float4v*)(fc1_f + j * 128 + k0);  // coalesced
            a0 += xv * fv[0]; a1 += xv * fv[1];
            a2 += xv * fv[2]; a3 += xv * fv[3];
        }
        wefft[(k0 + 0) * 512 + n] = a0;       // one-time scattered stores
        wefft[(k0 + 1) * 512 + n] = a1;
        wefft[(k0 + 2) * 512 + n] = a2;
        wefft[(k0 + 3) * 512 + n] = a3;
        return;
    }
    int tg = (blockIdx.x - 64) * 256 + tid;   // 0..511
    float s = x2hb_f[tg] + h2hb_f[tg];
    const float4v* xr = (const float4v*)(x2h_f + tg * 128);
    const float4v* bb = (const float4v*)fc1b_f;
    for (int j = 0; j < 32; j++) {
        float4v a = xr[j], b = bb[j];
        s += a[0] * b[0] + a[1] * b[1] + a[2] * b[2] + a[3] * b[3];
    }
    beff[tg] = s;
}

// ---------------------------------------------------------------------------
// K2 (1125 blocks x 256): table build + all elementwise prep (r11-proven),
// with the table store now in the r13 HW-verified N-PERMUTED layout:
//   logical n = w*64 + nt*16 + qq*4 + r  ->  p = w*64 + (nt>>1)*32 + qq*8
//                                               + (nt&1)*4 + r
// (value-identical; lets the rnn gather read one 64B line per 4 q-lanes).
// ---------------------------------------------------------------------------
__launch_bounds__(256)
__global__ void k2_kernel(const float* __restrict__ wefft, const float* __restrict__ beff,
                          const float* __restrict__ len_f, const float* __restrict__ ipd_f,
                          const int* __restrict__ xi, unsigned char* __restrict__ xc,
                          const float* __restrict__ h2h_f, const float* __restrict__ fc2_f,
                          const float* __restrict__ fc2b_f,
                          unsigned short* __restrict__ elen, unsigned short* __restrict__ eipd,
                          unsigned short* __restrict__ o_wh, unsigned short* __restrict__ o_fc2,
                          float* __restrict__ o_fc2b) {
    const int tid = threadIdx.x;
    if (blockIdx.x < 256) {
        int grp = blockIdx.x * 256 + tid;      // 0..65535
        int tab = grp >> 15;                   // 0: len, 1: ipd
        int g2  = grp & 32767;
        int v   = g2 >> 7;
        int nq  = (g2 & 127) * 4;              // logical n base (4 consecutive)
        const float* emb = (tab ? ipd_f : len_f) + v * 64;
        const float* wt  = wefft + tab * 64 * 512 + nq;
        float a0 = 0.f, a1 = 0.f, a2 = 0.f, a3 = 0.f;
#pragma unroll 8
        for (int k = 0; k < 64; k++) {
            float e = emb[k];
            float4v w = *(const float4v*)(wt + k * 512);
            a0 += e * w[0]; a1 += e * w[1]; a2 += e * w[2]; a3 += e * w[3];
        }
        if (tab) {
            float4v b4 = *(const float4v*)&beff[nq];
            a0 += b4[0]; a1 += b4[1]; a2 += b4[2]; a3 += b4[3];
        }
        // permuted store (r13-verified bijection)
        int nt = (nq >> 4) & 3, qq = (nq >> 2) & 3;
        int p0 = (nq & ~63) + ((nt >> 1) << 5) + qq * 8 + ((nt & 1) << 2);
        us4 o = { f2bf(a0), f2bf(a1), f2bf(a2), f2bf(a3) };
        unsigned short* dst = tab ? eipd : elen;
        *(us4*)&dst[v * 512 + p0] = o;
        return;
    }
    if (blockIdx.x < 512) {
        __shared__ int is64;
        if (tid == 0) {
            int nz = 0;
            for (int j = 1; j < 64; j += 2) nz |= xi[j];
            is64 = (nz == 0) ? 1 : 0;
        }
        __syncthreads();
        const int n = B_SZ * T_SZ * 2;
        const int i64 = is64;
        for (int i = (blockIdx.x - 256) * 256 + tid; i < n; i += 256 * 256) {
            int v = i64 ? xi[2 * i] : xi[i];
            v = v < 0 ? 0 : (v > 255 ? 255 : v);
            int b = i >> 8, r = i & 255, t = r >> 1, c = r & 1;
            xc[t * 2048 + b * 2 + c] = (unsigned char)v;
        }
        return;
    }
    const int N2 = 262144, N3 = 51200, N5 = 100;
    const int total = N2 + N3 + N5;
    for (int i = (blockIdx.x - 512) * 256 + tid; i < total; i += 613 * 256) {
        int j = i;
        if (j < N2) { o_wh[j] = f2bf(h2h_f[j]); continue; }
        j -= N2;
        if (j < N3) { o_fc2[j] = f2bf(fc2_f[j]); continue; }
        j -= N3;
        o_fc2b[j] = fc2b_f[j];
    }
}

// ---------------------------------------------------------------------------
// RNN v8: r11's proven v7 structure (317.6 us) with ONE change — the gather
// reads the N-PERMUTED tables as 4 x us8 (ecol = n0 + q*8): the 4 q-lanes of
// each table row cover one full 64B line -> 64 L1 line-transactions/wave/step
// (was 128). Unpack mapping HW-verified in r13 (absmax bit-identical).
// Everything else (bf16 Wh workspace, AGPR whr, swizzles, fast tanh, idx
// pipeline) is byte-identical to r11. r13 lesson: keep prep OUT of this
// kernel — inline f32 conversion caused 46 MB of loop spill.
// ---------------------------------------------------------------------------
__launch_bounds__(512, 2)
__global__ void rnn_kernel(const unsigned short* __restrict__ w_wh,
                           const unsigned char* __restrict__ w_xc,
                           const unsigned short* __restrict__ w_elen,
                           const unsigned short* __restrict__ w_eipd,
                           const unsigned short* __restrict__ w_fc2,
                           const float* __restrict__ w_fc2b,
                           float* __restrict__ out) {
    extern __shared__ unsigned short sm2[];
    unsigned short* sA = sm2;            // Wh k 384..511: 65536 ushorts (128 KB)
    unsigned short* sH = sm2 + 65536;    // h dbuf: 2 x 8192 ushorts (32 KB)

    const int tid  = threadIdx.x;
    const int wv   = tid >> 6;           // 0..7
    const int ln   = tid & 63;
    const int mcol = ln & 15;            // batch col within block
    const int q    = ln >> 4;
    const int g    = blockIdx.x;
    const int b0   = g * 16;
    const int n0   = wv * 64;            // wave owns hidden rows n0..n0+63

    // ---- stage Wh kt 12..15 into LDS (swizzled) ----
    for (int it = 0; it < 16; it++) {
        int chunk = it * 512 + tid;          // 0..8191
        int r = chunk >> 4, c = chunk & 15;
        uint4 v = *(const uint4*)(w_wh + r * 512 + 384 + c * 8);
        *(uint4*)&sA[r * 128 + ((c ^ (r & 15)) & 15) * 8] = v;
    }
    // ---- zero h buffer 0 ----
    {
        uint4 z = {0, 0, 0, 0};
        *(uint4*)&sH[tid * 8] = z;
        *(uint4*)&sH[(512 + tid) * 8] = z;
    }
    // ---- Wh kt 0..11 into registers: 48 frags = 192 regs (AGPR) ----
    short8 whr[4][12];
#pragma unroll
    for (int nt = 0; nt < 4; nt++)
#pragma unroll
        for (int kt = 0; kt < 12; kt++)
            whr[nt][kt] = *(const short8*)(w_wh + (n0 + nt * 16 + mcol) * 512 + kt * 32 + q * 8);

    // ---- strength-reduced swizzle offsets (ushort units) ----
    const int qlo = (q ^ (mcol & 3)) * 8;
    int ej[4];
#pragma unroll
    for (int j = 0; j < 4; j++)
        ej[j] = ((j * 4) ^ (mcol & 12)) * 8;
    const int base_b = mcol * 512 + qlo;          // h-read base
    const int fbase  = (n0 + mcol) * 128 + qlo;   // sA-read base
    int hw_off[4];
#pragma unroll
    for (int nt = 0; nt < 4; nt++) {
        int n = n0 + nt * 16 + q * 4;
        hw_off[nt] = mcol * 512 + (((n >> 3) ^ mcol) & 63) * 8 + (n & 7);
    }

    // ---- gather pipeline prologue (permuted bf16 tables, uchar2 idx) ----
    const int xb2  = (b0 + mcol) * 2;     // byte offset within a t-slice
    const int ecol = n0 + q * 8;          // permuted window offset
    us8 tL0, tL1, tI0, tI1;
    {
        unsigned int i0 = *(const unsigned short*)&w_xc[xb2];          // x[t=0]
        const unsigned short* eL = w_elen + (i0 & 255u) * 512 + ecol;
        const unsigned short* eI = w_eipd + (i0 >> 8) * 512 + ecol;
        tL0 = *(const us8*)eL;  tL1 = *(const us8*)(eL + 32);
        tI0 = *(const us8*)eI;  tI1 = *(const us8*)(eI + 32);
    }
    unsigned int idxP = *(const unsigned short*)&w_xc[2048 + xb2];     // x[t=1]

    __syncthreads();

    for (int t = 0; t < T_SZ; t++) {
        const unsigned short* hRd = sH + ((t & 1) << 13);
        unsigned short* hWr = sH + (((t + 1) & 1) << 13);

        // ---- acc init: unpack permuted us8 pairs (loads from t-1, landed) --
        float4v acc[4];
#pragma unroll
        for (int r = 0; r < 4; r++) {
            acc[0][r] = bf2f(tL0[r])     + bf2f(tI0[r]);
            acc[1][r] = bf2f(tL0[4 + r]) + bf2f(tI0[4 + r]);
            acc[2][r] = bf2f(tL1[r])     + bf2f(tI1[r]);
            acc[3][r] = bf2f(tL1[4 + r]) + bf2f(tI1[4 + r]);
        }
        // ---- issue next-step table loads (idxP resident -> no chain) ----
        if (t + 1 < T_SZ) {
            const unsigned short* eL = w_elen + (idxP & 255u) * 512 + ecol;
            const unsigned short* eI = w_eipd + (idxP >> 8) * 512 + ecol;
            tL0 = *(const us8*)eL;  tL1 = *(const us8*)(eL + 32);
            tI0 = *(const us8*)eI;  tI1 = *(const us8*)(eI + 32);
            if (t + 2 < T_SZ)
                idxP = *(const unsigned short*)&w_xc[(t + 2) * 2048 + xb2];
        }

        // ---- Wh MFMAs: kt 0..11 from regs ----
#pragma unroll
        for (int kt = 0; kt < 12; kt++) {
            short8 bh = *(const short8*)&hRd[base_b + ej[kt & 3] + (kt >> 2) * 128];
#pragma unroll
            for (int nt = 0; nt < 4; nt++)
                acc[nt] = mfma16(whr[nt][kt], bh, acc[nt]);
        }
        // ---- kt 12..15 from LDS ----
#pragma unroll
        for (int j = 0; j < 4; j++) {
            short8 bh = *(const short8*)&hRd[base_b + ej[j] + 384];
#pragma unroll
            for (int nt = 0; nt < 4; nt++) {
                short8 fa = *(const short8*)&sA[fbase + nt * 2048 + ej[j]];
                acc[nt] = mfma16(fa, bh, acc[nt]);
            }
        }

        // ---- fast tanh -> bf16, write h(t+1) into other buffer ----
#pragma unroll
        for (int nt = 0; nt < 4; nt++) {
            unsigned short o[4];
#pragma unroll
            for (int r = 0; r < 4; r++) {
                float e  = __expf(2.0f * acc[nt][r]);
                float th = 1.0f - 2.0f * __builtin_amdgcn_rcpf(e + 1.0f);
                o[r] = f2bf(th);
            }
            us4 v4 = { o[0], o[1], o[2], o[3] };
            *(us4*)&hWr[hw_off[nt]] = v4;
        }
        __syncthreads();   // h(t+1) visible to all waves before next step
    }

    // final h is in buffer 0 (T_SZ even)
    unsigned short* hF = sH;

    // ---- fc2 epilogue: waves 0..6 cover 112 >= 100 labels ----
    if (wv < 7) {
        int lA = wv * 16 + mcol; if (lA > 99) lA = 99;
        float4v a2 = {0.f, 0.f, 0.f, 0.f};
#pragma unroll
        for (int kt = 0; kt < 16; kt++) {
            short8 fa = *(const short8*)(w_fc2 + lA * 512 + kt * 32 + q * 8);
            short8 bh = *(const short8*)&hF[base_b + ej[kt & 3] + (kt >> 2) * 128];
            a2 = mfma16(fa, bh, a2);
        }
#pragma unroll
        for (int r = 0; r < 4; r++) {
            int l = wv * 16 + q * 4 + r;
            if (l < 100) out[(b0 + mcol) * 100 + l] = a2[r] + w_fc2b[l];
        }
    }
}

extern "C" void kernel_launch(void* const* d_in, const int* in_sizes, int n_in,
                              void* d_out, int out_size, void* d_ws, size_t ws_size,
                              hipStream_t stream) {
    unsigned char* base = (unsigned char*)d_ws;
    if (ws_size < (size_t)WS_NEED) {
        void* p = nullptr;
        hipGetSymbolAddress(&p, HIP_SYMBOL(g_blob));
        base = (unsigned char*)p;
    }
    unsigned char*  w_xc    = base + OFF_XC;
    unsigned short* w_wh    = (unsigned short*)(base + OFF_WH);
    unsigned short* w_fc2   = (unsigned short*)(base + OFF_FC2);
    float*          w_fc2b  = (float*)(base + OFF_FC2B);
    float*          w_wefft = (float*)(base + OFF_WEFFT);
    float*          w_beff  = (float*)(base + OFF_BEFF);
    unsigned short* w_elen  = (unsigned short*)(base + OFF_ELEN);
    unsigned short* w_eipd  = (unsigned short*)(base + OFF_EIPD);

    static bool attr_set = false;
    if (!attr_set) {
        hipFuncSetAttribute((const void*)rnn_kernel,
                            hipFuncAttributeMaxDynamicSharedMemorySize, 163840);
        attr_set = true;
    }

    k1_kernel<<<66, 256, 0, stream>>>(
        (const float*)d_in[3], (const float*)d_in[4],
        (const float*)d_in[5], (const float*)d_in[6], (const float*)d_in[8],
        w_wefft, w_beff);
    k2_kernel<<<1125, 256, 0, stream>>>(
        w_wefft, w_beff,
        (const float*)d_in[1], (const float*)d_in[2],
        (const int*)d_in[0], w_xc,
        (const float*)d_in[7], (const float*)d_in[9], (const float*)d_in[10],
        w_elen, w_eipd, w_wh, w_fc2, w_fc2b);
    rnn_kernel<<<64, 512, 163840, stream>>>(
        w_wh, w_xc, w_elen, w_eipd, w_fc2, w_fc2b, (float*)d_out);
}